// Round 1
// baseline (732.991 us; speedup 1.0000x reference)
//
#include <hip/hip_runtime.h>

#define DIM 128
#define GEMM_ROWS 16

// ---------------------------------------------------------------------------
// Count edge-only degrees (self-loops folded in later as +1).
// cnt_r counts receivers (-> out_degree), cnt_s counts senders (-> in_degree).
// ---------------------------------------------------------------------------
__global__ void degree_kernel(const int* __restrict__ senders,
                              const int* __restrict__ receivers,
                              int* __restrict__ cnt_s,
                              int* __restrict__ cnt_r,
                              int E) {
    int e = blockIdx.x * blockDim.x + threadIdx.x;
    if (e < E) {
        atomicAdd(&cnt_r[receivers[e]], 1);
        atomicAdd(&cnt_s[senders[e]], 1);
    }
}

// ---------------------------------------------------------------------------
// Transpose W [128 x 256] row-major -> Wt [256 x 128] so GEMM W-loads are
// lane-coalesced. Tiny one-shot kernel (32768 elements).
// ---------------------------------------------------------------------------
__global__ void transpose_w_kernel(const float* __restrict__ W,
                                   float* __restrict__ Wt) {
    int i = blockIdx.x * blockDim.x + threadIdx.x;  // 0..32767
    int d = i >> 8;     // 0..127 (output channel)
    int k = i & 255;    // 0..255 (input channel)
    Wt[k * DIM + d] = W[i];
}

// ---------------------------------------------------------------------------
// Edge scatter: one wave (64 lanes) per edge; lane handles 2 of 128 dims via
// float2. agg[r] += x[s] * rsqrt(cnt_r[s] + 1).
// Self-loop contribution is added in the GEMM staging (no atomics needed).
// ---------------------------------------------------------------------------
__global__ void scatter_kernel(const float* __restrict__ x,
                               const int* __restrict__ senders,
                               const int* __restrict__ receivers,
                               const int* __restrict__ cnt_r,
                               float* __restrict__ agg,
                               int E) {
    int lane = threadIdx.x & 63;
    int wave = (blockIdx.x * blockDim.x + threadIdx.x) >> 6;
    int nwaves = (gridDim.x * blockDim.x) >> 6;
    for (int e = wave; e < E; e += nwaves) {
        int s = senders[e];    // same address across wave -> HW broadcast
        int r = receivers[e];
        float scale = rsqrtf((float)(cnt_r[s] + 1));
        float2 v = ((const float2*)x)[(size_t)s * 64 + lane];
        float* dst = agg + (size_t)r * DIM + 2 * lane;
        atomicAdd(dst + 0, v.x * scale);
        atomicAdd(dst + 1, v.y * scale);
    }
}

// ---------------------------------------------------------------------------
// Fused finalize + GEMM.
// combined[n, 0:128]   = x[n]
// combined[n, 128:256] = (agg_raw[n] + x[n]*rsqrt(cnt_r+1)) * rsqrt(cnt_s+1)/(cnt_r+1)
// out[n, d] = sum_k combined[n,k] * Wt[k,d] + b[d]
//
// Block: 256 threads, GEMM_ROWS=16 output rows, 128 cols.
// col = tid & 127, row-group = tid >> 7 (8 rows each) -> 8 acc/thread.
// LDS combined reads are same-address across each wave -> broadcast (free).
// Wt loads are lane-consecutive -> coalesced, amortized 8x across rows.
// ---------------------------------------------------------------------------
__global__ __launch_bounds__(256) void gemm_kernel(
        const float* __restrict__ x,
        const float* __restrict__ agg,
        const int* __restrict__ cnt_r,
        const int* __restrict__ cnt_s,
        const float* __restrict__ Wt,
        const float* __restrict__ bias,
        float* __restrict__ out,
        int N) {
    __shared__ float smem[GEMM_ROWS * 256];
    __shared__ float s_onorm[GEMM_ROWS];
    __shared__ float s_fscale[GEMM_ROWS];

    int t = threadIdx.x;
    int row0 = blockIdx.x * GEMM_ROWS;

    // Per-row normalization scalars
    if (t < GEMM_ROWS) {
        int row = row0 + t;
        if (row < N) {
            float od = (float)(cnt_r[row] + 1);
            s_onorm[t]  = rsqrtf(od);
            s_fscale[t] = rsqrtf((float)(cnt_s[row] + 1)) / od;
        } else {
            s_onorm[t] = 0.f;
            s_fscale[t] = 0.f;
        }
    }
    __syncthreads();

    // Stage combined tile: GEMM_ROWS rows x 256 K, as 1024 float4 loads.
    for (int i = t; i < GEMM_ROWS * 64; i += 256) {
        int r = i >> 6;       // row within tile
        int j = i & 63;       // float4 slot within row: 0..31 = x, 32..63 = agg
        int row = row0 + r;
        float4 val;
        if (row < N) {
            if (j < 32) {
                val = ((const float4*)x)[(size_t)row * 32 + j];
            } else {
                int jj = j - 32;
                float4 a  = ((const float4*)agg)[(size_t)row * 32 + jj];
                float4 xv = ((const float4*)x)[(size_t)row * 32 + jj];
                float on = s_onorm[r], fs = s_fscale[r];
                val.x = (a.x + xv.x * on) * fs;
                val.y = (a.y + xv.y * on) * fs;
                val.z = (a.z + xv.z * on) * fs;
                val.w = (a.w + xv.w * on) * fs;
            }
        } else {
            val.x = val.y = val.z = val.w = 0.f;
        }
        ((float4*)&smem[r * 256])[j] = val;
    }
    __syncthreads();

    int col = t & 127;
    int rg  = t >> 7;   // 0 or 1; handles rows rg*8 .. rg*8+7
    float acc[8] = {0.f, 0.f, 0.f, 0.f, 0.f, 0.f, 0.f, 0.f};

    for (int k = 0; k < 256; k += 4) {
        float w0 = Wt[(k + 0) * DIM + col];
        float w1 = Wt[(k + 1) * DIM + col];
        float w2 = Wt[(k + 2) * DIM + col];
        float w3 = Wt[(k + 3) * DIM + col];
#pragma unroll
        for (int r = 0; r < 8; r++) {
            float4 c4 = *((const float4*)&smem[(rg * 8 + r) * 256 + k]);
            acc[r] += c4.x * w0 + c4.y * w1 + c4.z * w2 + c4.w * w3;
        }
    }

    float bb = bias[col];
#pragma unroll
    for (int r = 0; r < 8; r++) {
        int row = row0 + rg * 8 + r;
        if (row < N) out[(size_t)row * DIM + col] = acc[r] + bb;
    }
}

// ---------------------------------------------------------------------------
// Launch
// ---------------------------------------------------------------------------
extern "C" void kernel_launch(void* const* d_in, const int* in_sizes, int n_in,
                              void* d_out, int out_size, void* d_ws, size_t ws_size,
                              hipStream_t stream) {
    const float* x        = (const float*)d_in[0];
    const int*   senders  = (const int*)d_in[1];
    const int*   receivers= (const int*)d_in[2];
    // d_in[3] = n_nodes scalar (unused; derive from in_sizes)
    const float* W        = (const float*)d_in[4];
    const float* bias     = (const float*)d_in[5];
    float*       out      = (float*)d_out;

    int N = in_sizes[0] / DIM;   // 50000
    int E = in_sizes[1];         // 625000

    // Workspace layout (16B-aligned at each offset for N=50000):
    //   [0, 4N)              cnt_r (int)
    //   [4N, 8N)             cnt_s (int)
    //   [8N, 8N + 512N)      agg   (float, N x 128)
    //   [8N + 512N, +128KB)  Wt    (float, 256 x 128)
    char* ws = (char*)d_ws;
    int*   cnt_r = (int*)ws;
    int*   cnt_s = (int*)(ws + (size_t)N * 4);
    float* agg   = (float*)(ws + (size_t)N * 8);
    float* Wt    = (float*)(ws + (size_t)N * 8 + (size_t)N * 512);

    size_t zero_bytes = (size_t)N * 8 + (size_t)N * 512;
    hipMemsetAsync(d_ws, 0, zero_bytes, stream);

    transpose_w_kernel<<<DIM * 256 / 256, 256, 0, stream>>>(W, Wt);
    degree_kernel<<<(E + 255) / 256, 256, 0, stream>>>(senders, receivers, cnt_s, cnt_r, E);
    scatter_kernel<<<2048, 256, 0, stream>>>(x, senders, receivers, cnt_r, agg, E);
    gemm_kernel<<<(N + GEMM_ROWS - 1) / GEMM_ROWS, 256, 0, stream>>>(
        x, agg, cnt_r, cnt_s, Wt, bias, out, N);
}

// Round 2
// 416.146 us; speedup vs baseline: 1.7614x; 1.7614x over previous
//
#include <hip/hip_runtime.h>

#define DIM 128
#define GEMM_ROWS 16

// ---------------------------------------------------------------------------
// Count edge-only degrees (self-loops folded in later as +1).
// cnt_r counts receivers (-> out_degree), cnt_s counts senders (-> in_degree).
// ---------------------------------------------------------------------------
__global__ void degree_kernel(const int* __restrict__ senders,
                              const int* __restrict__ receivers,
                              int* __restrict__ cnt_s,
                              int* __restrict__ cnt_r,
                              int E) {
    int e = blockIdx.x * blockDim.x + threadIdx.x;
    if (e < E) {
        atomicAdd(&cnt_r[receivers[e]], 1);
        atomicAdd(&cnt_s[senders[e]], 1);
    }
}

// ---------------------------------------------------------------------------
// Transpose W [128 x 256] row-major -> Wt [256 x 128] (lane-coalesced GEMM).
// ---------------------------------------------------------------------------
__global__ void transpose_w_kernel(const float* __restrict__ W,
                                   float* __restrict__ Wt) {
    int i = blockIdx.x * blockDim.x + threadIdx.x;  // 0..32767
    int d = i >> 8;     // output channel
    int k = i & 255;    // input channel
    Wt[k * DIM + d] = W[i];
}

// ---------------------------------------------------------------------------
// Single-block exclusive scan of cnt_r[0..N) -> row_start, cursor.
// 1024 threads, each owns a contiguous chunk; Hillis-Steele over partials.
// ---------------------------------------------------------------------------
__global__ __launch_bounds__(1024) void scan_kernel(const int* __restrict__ cnt_r,
                                                    int* __restrict__ row_start,
                                                    int* __restrict__ cursor,
                                                    int N) {
    __shared__ int partial[1024];
    int t = threadIdx.x;
    int chunk = (N + 1023) / 1024;
    int begin = t * chunk;
    int end = begin + chunk; if (end > N) end = N;

    int sum = 0;
    for (int i = begin; i < end; i++) sum += cnt_r[i];
    partial[t] = sum;
    __syncthreads();

    for (int off = 1; off < 1024; off <<= 1) {
        int v = (t >= off) ? partial[t - off] : 0;
        __syncthreads();
        partial[t] += v;
        __syncthreads();
    }

    int run = partial[t] - sum;  // exclusive prefix of this thread's chunk
    for (int i = begin; i < end; i++) {
        row_start[i] = run;
        cursor[i]    = run;
        run += cnt_r[i];
    }
}

// ---------------------------------------------------------------------------
// Counting-sort fill: bucket each edge's SENDER under its receiver.
// 625K int atomics (vs 80M float atomics in the push-scatter design).
// ---------------------------------------------------------------------------
__global__ void fill_kernel(const int* __restrict__ senders,
                            const int* __restrict__ receivers,
                            int* __restrict__ cursor,
                            int* __restrict__ edge_src,
                            int E) {
    int e = blockIdx.x * blockDim.x + threadIdx.x;
    if (e < E) {
        int r = receivers[e];
        int pos = atomicAdd(&cursor[r], 1);
        edge_src[pos] = senders[e];
    }
}

// ---------------------------------------------------------------------------
// Pull-gather + finalize: one wave per node, lane owns 2 dims (float2).
// Edge srcs and their scales are batch-loaded per-lane, then __shfl-broadcast.
// agg[n] = (sum_e x[src_e]*rsqrt(cnt_r[src_e]+1) + x[n]*rsqrt(cnt_r[n]+1))
//          * rsqrt(cnt_s[n]+1) / (cnt_r[n]+1)
// Written exactly once -> no float atomics anywhere.
// ---------------------------------------------------------------------------
__global__ __launch_bounds__(256) void gather_kernel(
        const float* __restrict__ x,
        const int* __restrict__ edge_src,
        const int* __restrict__ row_start,
        const int* __restrict__ cnt_r,
        const int* __restrict__ cnt_s,
        float* __restrict__ agg,
        int N) {
    int lane = threadIdx.x & 63;
    int n = (blockIdx.x * blockDim.x + threadIdx.x) >> 6;
    if (n >= N) return;

    int start = row_start[n];
    int deg   = cnt_r[n];
    const float2* x2 = (const float2*)x;
    float2 acc; acc.x = 0.f; acc.y = 0.f;

    for (int base = 0; base < deg; base += 64) {
        int cnt = deg - base; if (cnt > 64) cnt = 64;
        int   src = 0;
        float sc  = 0.f;
        if (lane < cnt) {
            src = edge_src[start + base + lane];
            sc  = rsqrtf((float)(cnt_r[src] + 1));
        }
        for (int j = 0; j < cnt; j++) {
            int   s     = __shfl(src, j);
            float scale = __shfl(sc, j);
            float2 v = x2[(size_t)s * 64 + lane];
            acc.x += v.x * scale;
            acc.y += v.y * scale;
        }
    }

    float od    = (float)(cnt_r[n] + 1);
    float onorm = rsqrtf(od);
    float fs    = rsqrtf((float)(cnt_s[n] + 1)) / od;
    float2 xv = x2[(size_t)n * 64 + lane];
    acc.x = (acc.x + xv.x * onorm) * fs;
    acc.y = (acc.y + xv.y * onorm) * fs;
    ((float2*)agg)[(size_t)n * 64 + lane] = acc;
}

// ---------------------------------------------------------------------------
// GEMM: out = [x | agg] @ Wt + b.  (agg is already finalized.)
// Block: 256 threads, 16 rows x 128 cols; col = tid&127, 8 rows/thread.
// LDS reads are same-address per wave (broadcast, conflict-free); Wt loads
// lane-coalesced and amortized 8x.
// ---------------------------------------------------------------------------
__global__ __launch_bounds__(256) void gemm_kernel(
        const float* __restrict__ x,
        const float* __restrict__ agg,
        const float* __restrict__ Wt,
        const float* __restrict__ bias,
        float* __restrict__ out,
        int N) {
    __shared__ float smem[GEMM_ROWS * 256];
    int t = threadIdx.x;
    int row0 = blockIdx.x * GEMM_ROWS;

    for (int i = t; i < GEMM_ROWS * 64; i += 256) {
        int r = i >> 6;
        int j = i & 63;   // 0..31 -> x, 32..63 -> agg
        int row = row0 + r;
        float4 val;
        if (row < N) {
            val = (j < 32) ? ((const float4*)x)[(size_t)row * 32 + j]
                           : ((const float4*)agg)[(size_t)row * 32 + (j - 32)];
        } else {
            val.x = val.y = val.z = val.w = 0.f;
        }
        ((float4*)&smem[r * 256])[j] = val;
    }
    __syncthreads();

    int col = t & 127;
    int rg  = t >> 7;
    float acc[8] = {0.f, 0.f, 0.f, 0.f, 0.f, 0.f, 0.f, 0.f};

    for (int k = 0; k < 256; k += 4) {
        float w0 = Wt[(k + 0) * DIM + col];
        float w1 = Wt[(k + 1) * DIM + col];
        float w2 = Wt[(k + 2) * DIM + col];
        float w3 = Wt[(k + 3) * DIM + col];
#pragma unroll
        for (int r = 0; r < 8; r++) {
            float4 c4 = *((const float4*)&smem[(rg * 8 + r) * 256 + k]);
            acc[r] += c4.x * w0 + c4.y * w1 + c4.z * w2 + c4.w * w3;
        }
    }

    float bb = bias[col];
#pragma unroll
    for (int r = 0; r < 8; r++) {
        int row = row0 + rg * 8 + r;
        if (row < N) out[(size_t)row * DIM + col] = acc[r] + bb;
    }
}

// ---------------------------------------------------------------------------
// Launch
// ---------------------------------------------------------------------------
extern "C" void kernel_launch(void* const* d_in, const int* in_sizes, int n_in,
                              void* d_out, int out_size, void* d_ws, size_t ws_size,
                              hipStream_t stream) {
    const float* x         = (const float*)d_in[0];
    const int*   senders   = (const int*)d_in[1];
    const int*   receivers = (const int*)d_in[2];
    const float* W         = (const float*)d_in[4];
    const float* bias      = (const float*)d_in[5];
    float*       out       = (float*)d_out;

    int N = in_sizes[0] / DIM;   // 50000
    int E = in_sizes[1];         // 625000

    // Workspace layout (bytes, all 16B-aligned for N=50000, E=625000):
    //   cnt_r     [0,        4N)
    //   cnt_s     [4N,       8N)
    //   row_start [8N,       12N)
    //   cursor    [12N,      16N)
    //   edge_src  [16N,      16N+4E)
    //   agg       [16N+4E,   16N+4E+512N)
    //   Wt        [.., +128KB)
    char* ws = (char*)d_ws;
    size_t oN = (size_t)N * 4;
    int*   cnt_r     = (int*)ws;
    int*   cnt_s     = (int*)(ws + oN);
    int*   row_start = (int*)(ws + 2 * oN);
    int*   cursor    = (int*)(ws + 3 * oN);
    int*   edge_src  = (int*)(ws + 4 * oN);
    float* agg       = (float*)(ws + 4 * oN + (size_t)E * 4);
    float* Wt        = (float*)(ws + 4 * oN + (size_t)E * 4 + (size_t)N * 512);

    // Only the two counter arrays need zeroing.
    hipMemsetAsync(ws, 0, 2 * oN, stream);

    transpose_w_kernel<<<DIM * 256 / 256, 256, 0, stream>>>(W, Wt);
    degree_kernel<<<(E + 255) / 256, 256, 0, stream>>>(senders, receivers, cnt_s, cnt_r, E);
    scan_kernel<<<1, 1024, 0, stream>>>(cnt_r, row_start, cursor, N);
    fill_kernel<<<(E + 255) / 256, 256, 0, stream>>>(senders, receivers, cursor, edge_src, E);
    gather_kernel<<<(N * 64 + 255) / 256, 256, 0, stream>>>(
        x, edge_src, row_start, cnt_r, cnt_s, agg, N);
    gemm_kernel<<<(N + GEMM_ROWS - 1) / GEMM_ROWS, 256, 0, stream>>>(
        x, agg, Wt, bias, out, N);
}

// Round 4
// 286.765 us; speedup vs baseline: 2.5561x; 1.4512x over previous
//
#include <hip/hip_runtime.h>

#define DIM 128

// ---------------------------------------------------------------------------
// Count edge-only degrees (self-loops folded in later as +1).
// ---------------------------------------------------------------------------
__global__ void degree_kernel(const int* __restrict__ senders,
                              const int* __restrict__ receivers,
                              int* __restrict__ cnt_s,
                              int* __restrict__ cnt_r,
                              int E) {
    int e = blockIdx.x * blockDim.x + threadIdx.x;
    if (e < E) {
        atomicAdd(&cnt_r[receivers[e]], 1);
        atomicAdd(&cnt_s[senders[e]], 1);
    }
}

// ---------------------------------------------------------------------------
// Transpose W [128 x 256] -> Wt [256 x 128] (lane-coalesced GEMM staging).
// ---------------------------------------------------------------------------
__global__ void transpose_w_kernel(const float* __restrict__ W,
                                   float* __restrict__ Wt) {
    int i = blockIdx.x * blockDim.x + threadIdx.x;  // 0..32767
    int d = i >> 8;
    int k = i & 255;
    Wt[k * DIM + d] = W[i];
}

// ---------------------------------------------------------------------------
// 3-phase parallel exclusive scan of cnt_r -> row_start, cursor.
// ---------------------------------------------------------------------------
__global__ __launch_bounds__(256) void scan_phase_a(const int* __restrict__ cnt_r,
                                                    int* __restrict__ bsum, int N) {
    __shared__ int red[256];
    int t = threadIdx.x;
    int i = blockIdx.x * 256 + t;
    red[t] = (i < N) ? cnt_r[i] : 0;
    __syncthreads();
    for (int s = 128; s > 0; s >>= 1) {
        if (t < s) red[t] += red[t + s];
        __syncthreads();
    }
    if (t == 0) bsum[blockIdx.x] = red[0];
}

__global__ __launch_bounds__(256) void scan_phase_b(const int* __restrict__ bsum,
                                                    int* __restrict__ boff, int NB) {
    __shared__ int sh[256];
    int t = threadIdx.x;
    int v = (t < NB) ? bsum[t] : 0;
    sh[t] = v;
    __syncthreads();
    for (int off = 1; off < 256; off <<= 1) {
        int u = (t >= off) ? sh[t - off] : 0;
        __syncthreads();
        sh[t] += u;
        __syncthreads();
    }
    if (t < NB) boff[t] = sh[t] - v;  // exclusive
}

__global__ __launch_bounds__(256) void scan_phase_c(const int* __restrict__ cnt_r,
                                                    const int* __restrict__ boff,
                                                    int* __restrict__ row_start,
                                                    int* __restrict__ cursor, int N) {
    __shared__ int sh[256];
    int t = threadIdx.x;
    int i = blockIdx.x * 256 + t;
    int v = (i < N) ? cnt_r[i] : 0;
    sh[t] = v;
    __syncthreads();
    for (int off = 1; off < 256; off <<= 1) {
        int u = (t >= off) ? sh[t - off] : 0;
        __syncthreads();
        sh[t] += u;
        __syncthreads();
    }
    if (i < N) {
        int excl = sh[t] - v + boff[blockIdx.x];
        row_start[i] = excl;
        cursor[i]    = excl;
    }
}

// ---------------------------------------------------------------------------
// Counting-sort fill: bucket each edge's SENDER under its receiver.
// ---------------------------------------------------------------------------
__global__ void fill_kernel(const int* __restrict__ senders,
                            const int* __restrict__ receivers,
                            int* __restrict__ cursor,
                            int* __restrict__ edge_src,
                            int E) {
    int e = blockIdx.x * blockDim.x + threadIdx.x;
    if (e < E) {
        int r = receivers[e];
        int pos = atomicAdd(&cursor[r], 1);
        edge_src[pos] = senders[e];
    }
}

// ---------------------------------------------------------------------------
// Pull-gather + finalize: one wave per node, lane owns 2 dims (float2).
// ---------------------------------------------------------------------------
__global__ __launch_bounds__(256) void gather_kernel(
        const float* __restrict__ x,
        const int* __restrict__ edge_src,
        const int* __restrict__ row_start,
        const int* __restrict__ cnt_r,
        const int* __restrict__ cnt_s,
        float* __restrict__ agg,
        int N) {
    int lane = threadIdx.x & 63;
    int n = (blockIdx.x * blockDim.x + threadIdx.x) >> 6;
    if (n >= N) return;

    int start = row_start[n];
    int deg   = cnt_r[n];
    const float2* x2 = (const float2*)x;
    float2 acc; acc.x = 0.f; acc.y = 0.f;

    for (int base = 0; base < deg; base += 64) {
        int cnt = deg - base; if (cnt > 64) cnt = 64;
        int   src = 0;
        float sc  = 0.f;
        if (lane < cnt) {
            src = edge_src[start + base + lane];
            sc  = rsqrtf((float)(cnt_r[src] + 1));
        }
        for (int j = 0; j < cnt; j++) {
            int   s     = __shfl(src, j);
            float scale = __shfl(sc, j);
            float2 v = x2[(size_t)s * 64 + lane];
            acc.x += v.x * scale;
            acc.y += v.y * scale;
        }
    }

    float od    = (float)(cnt_r[n] + 1);
    float onorm = rsqrtf(od);
    float fs    = rsqrtf((float)(cnt_s[n] + 1)) / od;
    float2 xv = x2[(size_t)n * 64 + lane];
    acc.x = (acc.x + xv.x * onorm) * fs;
    acc.y = (acc.y + xv.y * onorm) * fs;
    ((float2*)agg)[(size_t)n * 64 + lane] = acc;
}

// ---------------------------------------------------------------------------
// Register-blocked GEMM: out = [x | agg] @ Wt + b.
// Block tile 128x128, 256 threads, 8x8 per thread, K-tile 32.
// Cs: stride 32, k-group XOR-swizzled by (row>>3)&7 -> conflict-free reads.
// Ws: 8-float col-groups at stride 12 within a 192-float k-row
//     (16 groups * 12 = 192; read aliasing is 2-way max = free).
// ---------------------------------------------------------------------------
__global__ __launch_bounds__(256) void gemm_kernel(
        const float* __restrict__ x,
        const float* __restrict__ agg,
        const float* __restrict__ Wt,
        const float* __restrict__ bias,
        float* __restrict__ out,
        int N) {
    __shared__ float Cs[128 * 32];    // 16 KB
    __shared__ float Ws[32 * 192];    // 24 KB  (row stride 192!)

    int t  = threadIdx.x;
    int tr = t >> 4;        // 0..15 thread-row
    int tc = t & 15;        // 0..15 thread-col
    int row0 = blockIdx.x * 128;
    int r0 = tr * 8;
    int c0 = tc * 8;

    float acc[8][8];
#pragma unroll
    for (int i = 0; i < 8; i++)
#pragma unroll
        for (int j = 0; j < 8; j++) acc[i][j] = 0.f;

    int cr = t >> 1;        // staging row for C (0..127)
    int chalf = t & 1;      // staging kg half
    int swz = tr & 7;

    for (int kt = 0; kt < 8; kt++) {
        // ---- stage C tile: 128 rows x 32 k ----
        const float* src = (kt < 4) ? x : agg;
        int kf4 = (kt & 3) * 8;           // f4 offset within the 128-float row
        int grow = row0 + cr;
#pragma unroll
        for (int q = 0; q < 4; q++) {
            int kg = chalf * 4 + q;
            float4 v;
            if (grow < N) v = ((const float4*)src)[(size_t)grow * 32 + kf4 + kg];
            else { v.x = v.y = v.z = v.w = 0.f; }
            int phys = kg ^ ((cr >> 3) & 7);
            *(float4*)&Cs[cr * 32 + phys * 4] = v;
        }
        // ---- stage Wt tile: 32 k x 128 cols ----
#pragma unroll
        for (int p = 0; p < 4; p++) {
            int k = p * 8 + (t >> 5);
            int f4i = t & 31;
            float4 v = ((const float4*)Wt)[((size_t)(kt * 32 + k)) * 32 + f4i];
            int g = f4i >> 1, h = f4i & 1;
            *(float4*)&Ws[k * 192 + g * 12 + h * 4] = v;
        }
        __syncthreads();

        // ---- compute ----
        for (int kk = 0; kk < 32; kk += 4) {
            int kgl = kk >> 2;
            int phys4 = ((kgl ^ swz) << 2);
            float4 a[8];
#pragma unroll
            for (int i = 0; i < 8; i++)
                a[i] = *(const float4*)&Cs[(r0 + i) * 32 + phys4];
            float4 b0[4], b1[4];
#pragma unroll
            for (int j = 0; j < 4; j++) {
                b0[j] = *(const float4*)&Ws[(kk + j) * 192 + tc * 12];
                b1[j] = *(const float4*)&Ws[(kk + j) * 192 + tc * 12 + 4];
            }
#pragma unroll
            for (int j = 0; j < 4; j++) {
#pragma unroll
                for (int i = 0; i < 8; i++) {
                    float av = ((const float*)&a[i])[j];
                    acc[i][0] += av * b0[j].x;
                    acc[i][1] += av * b0[j].y;
                    acc[i][2] += av * b0[j].z;
                    acc[i][3] += av * b0[j].w;
                    acc[i][4] += av * b1[j].x;
                    acc[i][5] += av * b1[j].y;
                    acc[i][6] += av * b1[j].z;
                    acc[i][7] += av * b1[j].w;
                }
            }
        }
        __syncthreads();
    }

    // ---- epilogue ----
    float4 bb0 = ((const float4*)bias)[c0 >> 2];
    float4 bb1 = ((const float4*)bias)[(c0 >> 2) + 1];
#pragma unroll
    for (int i = 0; i < 8; i++) {
        int row = row0 + r0 + i;
        if (row < N) {
            float4 o0, o1;
            o0.x = acc[i][0] + bb0.x; o0.y = acc[i][1] + bb0.y;
            o0.z = acc[i][2] + bb0.z; o0.w = acc[i][3] + bb0.w;
            o1.x = acc[i][4] + bb1.x; o1.y = acc[i][5] + bb1.y;
            o1.z = acc[i][6] + bb1.z; o1.w = acc[i][7] + bb1.w;
            ((float4*)out)[(size_t)row * 32 + (c0 >> 2)]     = o0;
            ((float4*)out)[(size_t)row * 32 + (c0 >> 2) + 1] = o1;
        }
    }
}

// ---------------------------------------------------------------------------
// Launch
// ---------------------------------------------------------------------------
extern "C" void kernel_launch(void* const* d_in, const int* in_sizes, int n_in,
                              void* d_out, int out_size, void* d_ws, size_t ws_size,
                              hipStream_t stream) {
    const float* x         = (const float*)d_in[0];
    const int*   senders   = (const int*)d_in[1];
    const int*   receivers = (const int*)d_in[2];
    const float* W         = (const float*)d_in[4];
    const float* bias      = (const float*)d_in[5];
    float*       out       = (float*)d_out;

    int N = in_sizes[0] / DIM;   // 50000
    int E = in_sizes[1];         // 625000
    int NB = (N + 255) / 256;    // 196 scan blocks (must be <= 256)

    // Workspace layout (bytes, 16B-aligned):
    char* ws = (char*)d_ws;
    size_t oN = (size_t)N * 4;
    int*   cnt_r     = (int*)ws;
    int*   cnt_s     = (int*)(ws + oN);
    int*   row_start = (int*)(ws + 2 * oN);
    int*   cursor    = (int*)(ws + 3 * oN);
    int*   bsum      = (int*)(ws + 4 * oN);
    int*   boff      = (int*)(ws + 4 * oN + 4096);
    int*   edge_src  = (int*)(ws + 4 * oN + 8192);
    float* agg       = (float*)(ws + 4 * oN + 8192 + (size_t)E * 4);
    float* Wt        = (float*)(ws + 4 * oN + 8192 + (size_t)E * 4 + (size_t)N * 512);

    // Only the two counter arrays need zeroing.
    hipMemsetAsync(ws, 0, 2 * oN, stream);

    transpose_w_kernel<<<DIM * 256 / 256, 256, 0, stream>>>(W, Wt);
    degree_kernel<<<(E + 255) / 256, 256, 0, stream>>>(senders, receivers, cnt_s, cnt_r, E);
    scan_phase_a<<<NB, 256, 0, stream>>>(cnt_r, bsum, N);
    scan_phase_b<<<1, 256, 0, stream>>>(bsum, boff, NB);
    scan_phase_c<<<NB, 256, 0, stream>>>(cnt_r, boff, row_start, cursor, N);
    fill_kernel<<<(E + 255) / 256, 256, 0, stream>>>(senders, receivers, cursor, edge_src, E);
    gather_kernel<<<(N * 64 + 255) / 256, 256, 0, stream>>>(
        x, edge_src, row_start, cnt_r, cnt_s, agg, N);
    gemm_kernel<<<(N + 127) / 128, 256, 0, stream>>>(x, agg, Wt, bias, out, N);
}

// Round 5
// 226.837 us; speedup vs baseline: 3.2314x; 1.2642x over previous
//
#include <hip/hip_runtime.h>

#define DIM 128
#define BM 128
#define BK 32

typedef __attribute__((ext_vector_type(8))) short short8;
typedef __attribute__((ext_vector_type(4))) float f32x4;

// bf16 helpers (RNE), values are finite so no NaN handling needed.
__device__ __forceinline__ unsigned short f2bf(float f) {
    unsigned int b = __float_as_uint(f);
    return (unsigned short)((b + 0x7fffu + ((b >> 16) & 1u)) >> 16);
}
__device__ __forceinline__ float bf_lo(unsigned int u) {
    return __uint_as_float(u << 16);
}
__device__ __forceinline__ float bf_hi(unsigned int u) {
    return __uint_as_float(u & 0xffff0000u);
}

// ---------------------------------------------------------------------------
// Prep: convert x -> x_bf and W -> W_bf (packed uint = 2 bf16), and count
// edge-only degrees (self-loops folded in later as +1). One dispatch.
// ---------------------------------------------------------------------------
__global__ void prep_kernel(const float2* __restrict__ x2,
                            const float2* __restrict__ W2,
                            const int* __restrict__ senders,
                            const int* __restrict__ receivers,
                            unsigned int* __restrict__ xb,
                            unsigned int* __restrict__ Wb,
                            int* __restrict__ cnt_s,
                            int* __restrict__ cnt_r,
                            int nx2, int nw2, int E) {
    int i = blockIdx.x * blockDim.x + threadIdx.x;
    if (i < nw2) {
        float2 w = W2[i];
        Wb[i] = (unsigned int)f2bf(w.x) | ((unsigned int)f2bf(w.y) << 16);
    }
    if (i < E) {
        atomicAdd(&cnt_r[receivers[i]], 1);
        atomicAdd(&cnt_s[senders[i]], 1);
    }
    if (i < nx2) {
        float2 v = x2[i];
        xb[i] = (unsigned int)f2bf(v.x) | ((unsigned int)f2bf(v.y) << 16);
    }
}

// ---------------------------------------------------------------------------
// 3-phase parallel exclusive scan of cnt_r -> row_start, cursor.
// ---------------------------------------------------------------------------
__global__ __launch_bounds__(256) void scan_phase_a(const int* __restrict__ cnt_r,
                                                    int* __restrict__ bsum, int N) {
    __shared__ int red[256];
    int t = threadIdx.x;
    int i = blockIdx.x * 256 + t;
    red[t] = (i < N) ? cnt_r[i] : 0;
    __syncthreads();
    for (int s = 128; s > 0; s >>= 1) {
        if (t < s) red[t] += red[t + s];
        __syncthreads();
    }
    if (t == 0) bsum[blockIdx.x] = red[0];
}

__global__ __launch_bounds__(256) void scan_phase_b(const int* __restrict__ bsum,
                                                    int* __restrict__ boff, int NB) {
    __shared__ int sh[256];
    int t = threadIdx.x;
    int v = (t < NB) ? bsum[t] : 0;
    sh[t] = v;
    __syncthreads();
    for (int off = 1; off < 256; off <<= 1) {
        int u = (t >= off) ? sh[t - off] : 0;
        __syncthreads();
        sh[t] += u;
        __syncthreads();
    }
    if (t < NB) boff[t] = sh[t] - v;  // exclusive
}

__global__ __launch_bounds__(256) void scan_phase_c(const int* __restrict__ cnt_r,
                                                    const int* __restrict__ boff,
                                                    int* __restrict__ row_start,
                                                    int* __restrict__ cursor, int N) {
    __shared__ int sh[256];
    int t = threadIdx.x;
    int i = blockIdx.x * 256 + t;
    int v = (i < N) ? cnt_r[i] : 0;
    sh[t] = v;
    __syncthreads();
    for (int off = 1; off < 256; off <<= 1) {
        int u = (t >= off) ? sh[t - off] : 0;
        __syncthreads();
        sh[t] += u;
        __syncthreads();
    }
    if (i < N) {
        int excl = sh[t] - v + boff[blockIdx.x];
        row_start[i] = excl;
        cursor[i]    = excl;
    }
}

// ---------------------------------------------------------------------------
// Counting-sort fill: bucket each edge's SENDER under its receiver.
// ---------------------------------------------------------------------------
__global__ void fill_kernel(const int* __restrict__ senders,
                            const int* __restrict__ receivers,
                            int* __restrict__ cursor,
                            int* __restrict__ edge_src,
                            int E) {
    int e = blockIdx.x * blockDim.x + threadIdx.x;
    if (e < E) {
        int r = receivers[e];
        int pos = atomicAdd(&cursor[r], 1);
        edge_src[pos] = senders[e];
    }
}

// ---------------------------------------------------------------------------
// Pull-gather + finalize in bf16: one wave per node, lane owns 2 dims (uint).
// Inner loop unrolled x4 with independent loads for MLP. Writes agg_bf once.
// ---------------------------------------------------------------------------
__global__ __launch_bounds__(256) void gather_kernel(
        const unsigned int* __restrict__ xb,     // [NP][64] uints (2 bf16 each)
        const int* __restrict__ edge_src,
        const int* __restrict__ row_start,
        const int* __restrict__ cnt_r,
        const int* __restrict__ cnt_s,
        unsigned int* __restrict__ aggb,         // [NP][64] uints
        int N) {
    int lane = threadIdx.x & 63;
    int n = (blockIdx.x * blockDim.x + threadIdx.x) >> 6;
    if (n >= N) return;

    int start = row_start[n];
    int deg   = cnt_r[n];
    float ax = 0.f, ay = 0.f;

    for (int base = 0; base < deg; base += 64) {
        int cnt = deg - base; if (cnt > 64) cnt = 64;
        int   src = 0;
        float sc  = 0.f;
        if (lane < cnt) {
            src = edge_src[start + base + lane];
            sc  = rsqrtf((float)(cnt_r[src] + 1));
        }
        int j = 0;
        for (; j + 4 <= cnt; j += 4) {
            int   s0 = __shfl(src, j + 0), s1 = __shfl(src, j + 1);
            int   s2 = __shfl(src, j + 2), s3 = __shfl(src, j + 3);
            float c0 = __shfl(sc, j + 0),  c1 = __shfl(sc, j + 1);
            float c2 = __shfl(sc, j + 2),  c3 = __shfl(sc, j + 3);
            unsigned int u0 = xb[(size_t)s0 * 64 + lane];
            unsigned int u1 = xb[(size_t)s1 * 64 + lane];
            unsigned int u2 = xb[(size_t)s2 * 64 + lane];
            unsigned int u3 = xb[(size_t)s3 * 64 + lane];
            ax += bf_lo(u0) * c0 + bf_lo(u1) * c1 + bf_lo(u2) * c2 + bf_lo(u3) * c3;
            ay += bf_hi(u0) * c0 + bf_hi(u1) * c1 + bf_hi(u2) * c2 + bf_hi(u3) * c3;
        }
        for (; j < cnt; j++) {
            int   s = __shfl(src, j);
            float c = __shfl(sc, j);
            unsigned int u = xb[(size_t)s * 64 + lane];
            ax += bf_lo(u) * c;
            ay += bf_hi(u) * c;
        }
    }

    float od    = (float)(cnt_r[n] + 1);
    float onorm = rsqrtf(od);
    float fs    = rsqrtf((float)(cnt_s[n] + 1)) / od;
    unsigned int u = xb[(size_t)n * 64 + lane];
    ax = (ax + bf_lo(u) * onorm) * fs;
    ay = (ay + bf_hi(u) * onorm) * fs;
    aggb[(size_t)n * 64 + lane] =
        (unsigned int)f2bf(ax) | ((unsigned int)f2bf(ay) << 16);
}

// ---------------------------------------------------------------------------
// MFMA bf16 GEMM: out = [x_bf | agg_bf] @ W_bf^T + b  (fp32 accum/output).
// Block 128x128, 4 waves in 2x2; each wave 4x4 tiles of 16x16x32 mfma.
// A rows are k-contiguous; W_bf [n][k] is exactly the B^T layout MFMA wants.
// C/D layout: col = lane&15, row = (lane>>4)*4 + reg   [m89/m91-verified].
// ---------------------------------------------------------------------------
__global__ __launch_bounds__(256) void gemm_kernel(
        const unsigned short* __restrict__ x_bf,   // [NP][128]
        const unsigned short* __restrict__ agg_bf, // [NP][128]
        const unsigned short* __restrict__ W_bf,   // [128][256]
        const float* __restrict__ bias,
        float* __restrict__ out, int N) {
    __shared__ unsigned short As[BM * BK];    // 8 KB
    __shared__ unsigned short Bs[DIM * BK];   // 8 KB

    int t    = threadIdx.x;
    int lane = t & 63;
    int w    = t >> 6;
    int wr   = w >> 1, wc = w & 1;
    int row0 = blockIdx.x * BM;

    f32x4 acc[4][4];
#pragma unroll
    for (int i = 0; i < 4; i++)
#pragma unroll
        for (int j = 0; j < 4; j++) acc[i][j] = (f32x4){0.f, 0.f, 0.f, 0.f};

    for (int kt = 0; kt < 8; kt++) {
        const unsigned short* src = (kt < 4) ? x_bf : agg_bf;
        int k0 = (kt & 3) * BK;
        // Stage A tile: 128 rows x 32 k (2 passes x 256 threads x 8 bf16).
#pragma unroll
        for (int p = 0; p < 2; p++) {
            int idx = p * 256 + t;
            int row = idx >> 2;
            int ch  = idx & 3;
            uint4 v = *(const uint4*)&src[(size_t)(row0 + row) * 128 + k0 + ch * 8];
            *(uint4*)&As[row * BK + ch * 8] = v;
        }
        // Stage B tile: 128 n x 32 k from W_bf.
#pragma unroll
        for (int p = 0; p < 2; p++) {
            int idx = p * 256 + t;
            int n   = idx >> 2;
            int ch  = idx & 3;
            uint4 v = *(const uint4*)&W_bf[(size_t)n * 256 + kt * BK + ch * 8];
            *(uint4*)&Bs[n * BK + ch * 8] = v;
        }
        __syncthreads();

        short8 a[4], b[4];
#pragma unroll
        for (int i = 0; i < 4; i++)
            a[i] = *(const short8*)&As[(wr * 64 + i * 16 + (lane & 15)) * BK + (lane >> 4) * 8];
#pragma unroll
        for (int j = 0; j < 4; j++)
            b[j] = *(const short8*)&Bs[(wc * 64 + j * 16 + (lane & 15)) * BK + (lane >> 4) * 8];
#pragma unroll
        for (int i = 0; i < 4; i++)
#pragma unroll
            for (int j = 0; j < 4; j++)
                acc[i][j] = __builtin_amdgcn_mfma_f32_16x16x32_bf16(a[i], b[j], acc[i][j], 0, 0, 0);
        __syncthreads();
    }

    int cq = lane >> 4;
    int cl = lane & 15;
#pragma unroll
    for (int j = 0; j < 4; j++) {
        int col = wc * 64 + j * 16 + cl;
        float bb = bias[col];
#pragma unroll
        for (int i = 0; i < 4; i++) {
            int rbase = row0 + wr * 64 + i * 16 + cq * 4;
#pragma unroll
            for (int r = 0; r < 4; r++) {
                int row = rbase + r;
                if (row < N) out[(size_t)row * DIM + col] = acc[i][j][r] + bb;
            }
        }
    }
}

// ---------------------------------------------------------------------------
// Launch
// ---------------------------------------------------------------------------
extern "C" void kernel_launch(void* const* d_in, const int* in_sizes, int n_in,
                              void* d_out, int out_size, void* d_ws, size_t ws_size,
                              hipStream_t stream) {
    const float* x         = (const float*)d_in[0];
    const int*   senders   = (const int*)d_in[1];
    const int*   receivers = (const int*)d_in[2];
    const float* W         = (const float*)d_in[4];
    const float* bias      = (const float*)d_in[5];
    float*       out       = (float*)d_out;

    int N  = in_sizes[0] / DIM;            // 50000
    int E  = in_sizes[1];                  // 625000
    int NB = (N + 255) / 256;              // 196 (must be <= 256)
    int NP = ((N + BM - 1) / BM) * BM;     // 50048, padded rows for GEMM staging

    // Workspace layout (bytes, 16B-aligned):
    //   cnt_r, cnt_s, row_start, cursor : 4N each
    //   bsum, boff                      : 4 KB each
    //   edge_src                        : 4E
    //   x_bf                            : NP*256
    //   agg_bf                          : NP*256
    //   W_bf                            : 64 KB
    char* ws = (char*)d_ws;
    size_t oN = (size_t)N * 4;
    int*   cnt_r     = (int*)ws;
    int*   cnt_s     = (int*)(ws + oN);
    int*   row_start = (int*)(ws + 2 * oN);
    int*   cursor    = (int*)(ws + 3 * oN);
    int*   bsum      = (int*)(ws + 4 * oN);
    int*   boff     = (int*)(ws + 4 * oN + 4096);
    int*   edge_src  = (int*)(ws + 4 * oN + 8192);
    unsigned short* x_bf   = (unsigned short*)(ws + 4 * oN + 8192 + (size_t)E * 4);
    unsigned short* agg_bf = x_bf + (size_t)NP * DIM;
    unsigned short* W_bf   = agg_bf + (size_t)NP * DIM;

    // Only the two counter arrays need zeroing.
    hipMemsetAsync(ws, 0, 2 * oN, stream);

    int nx2 = N * 64;        // float2 count of x
    int nw2 = DIM * 256 / 2; // float2 count of W = 16384
    int prep_threads = nx2;  // covers E and nw2 too
    prep_kernel<<<(prep_threads + 255) / 256, 256, 0, stream>>>(
        (const float2*)x, (const float2*)W, senders, receivers,
        (unsigned int*)x_bf, (unsigned int*)W_bf, cnt_s, cnt_r, nx2, nw2, E);
    scan_phase_a<<<NB, 256, 0, stream>>>(cnt_r, bsum, N);
    scan_phase_b<<<1, 256, 0, stream>>>(bsum, boff, NB);
    scan_phase_c<<<NB, 256, 0, stream>>>(cnt_r, boff, row_start, cursor, N);
    fill_kernel<<<(E + 255) / 256, 256, 0, stream>>>(senders, receivers, cursor, edge_src, E);
    gather_kernel<<<(N * 64 + 255) / 256, 256, 0, stream>>>(
        (const unsigned int*)x_bf, edge_src, row_start, cnt_r, cnt_s,
        (unsigned int*)agg_bf, N);
    gemm_kernel<<<(N + BM - 1) / BM, 256, 0, stream>>>(
        x_bf, agg_bf, W_bf, bias, out, N);
}

// Round 6
// 199.526 us; speedup vs baseline: 3.6737x; 1.1369x over previous
//
#include <hip/hip_runtime.h>

#define DIM 128
#define BM 128
#define BK 32
#define PAD 16   // ints per counter slot -> one 64B line per counter

typedef __attribute__((ext_vector_type(8))) short short8;
typedef __attribute__((ext_vector_type(4))) float f32x4;

// bf16 helpers (RNE), values are finite so no NaN handling needed.
__device__ __forceinline__ unsigned short f2bf(float f) {
    unsigned int b = __float_as_uint(f);
    return (unsigned short)((b + 0x7fffu + ((b >> 16) & 1u)) >> 16);
}
__device__ __forceinline__ float bf_lo(unsigned int u) {
    return __uint_as_float(u << 16);
}
__device__ __forceinline__ float bf_hi(unsigned int u) {
    return __uint_as_float(u & 0xffff0000u);
}
__device__ __forceinline__ uint2 pack4(float4 v) {
    uint2 r;
    r.x = (unsigned int)f2bf(v.x) | ((unsigned int)f2bf(v.y) << 16);
    r.y = (unsigned int)f2bf(v.z) | ((unsigned int)f2bf(v.w) << 16);
    return r;
}

// ---------------------------------------------------------------------------
// Prep: x->bf16, W->bf16, degree counts on LINE-PADDED counters (kills MALL
// per-line RMW serialization), and per-edge bucket rank from the atomic return.
// ---------------------------------------------------------------------------
__global__ void prep_kernel(const float4* __restrict__ x4,
                            const float4* __restrict__ W4,
                            const int* __restrict__ senders,
                            const int* __restrict__ receivers,
                            uint2* __restrict__ xb4,
                            uint2* __restrict__ Wb4,
                            int* __restrict__ cnt_r_pad,
                            int* __restrict__ cnt_s_pad,
                            int* __restrict__ rank,
                            int nx4, int nw4, int E) {
    int i = blockIdx.x * blockDim.x + threadIdx.x;
    if (i < nw4) Wb4[i] = pack4(W4[i]);
    if (i < E) {
        int r = receivers[i];
        int s = senders[i];
        rank[i] = atomicAdd(&cnt_r_pad[r * PAD], 1);
        atomicAdd(&cnt_s_pad[s * PAD], 1);
    }
    if (i < nx4) xb4[i] = pack4(x4[i]);
}

// ---------------------------------------------------------------------------
// 3-phase parallel exclusive scan of padded cnt_r -> row_start (+derived).
// ---------------------------------------------------------------------------
__global__ __launch_bounds__(256) void scan_phase_a(const int* __restrict__ cnt_r_pad,
                                                    int* __restrict__ bsum, int N) {
    __shared__ int red[256];
    int t = threadIdx.x;
    int i = blockIdx.x * 256 + t;
    red[t] = (i < N) ? cnt_r_pad[i * PAD] : 0;
    __syncthreads();
    for (int s = 128; s > 0; s >>= 1) {
        if (t < s) red[t] += red[t + s];
        __syncthreads();
    }
    if (t == 0) bsum[blockIdx.x] = red[0];
}

__global__ __launch_bounds__(256) void scan_phase_b(const int* __restrict__ bsum,
                                                    int* __restrict__ boff, int NB) {
    __shared__ int sh[256];
    int t = threadIdx.x;
    int v = (t < NB) ? bsum[t] : 0;
    sh[t] = v;
    __syncthreads();
    for (int off = 1; off < 256; off <<= 1) {
        int u = (t >= off) ? sh[t - off] : 0;
        __syncthreads();
        sh[t] += u;
        __syncthreads();
    }
    if (t < NB) boff[t] = sh[t] - v;  // exclusive
}

// Also emits sscale[i] = rsqrt(cnt_r+1) (per-edge scale, indexed by src) and
// fin2[i] = {onorm, fs} for gather's finalize; row_start[N] = E.
__global__ __launch_bounds__(256) void scan_phase_c(const int* __restrict__ cnt_r_pad,
                                                    const int* __restrict__ cnt_s_pad,
                                                    const int* __restrict__ boff,
                                                    int* __restrict__ row_start,
                                                    float* __restrict__ sscale,
                                                    float2* __restrict__ fin2,
                                                    int N) {
    __shared__ int sh[256];
    int t = threadIdx.x;
    int i = blockIdx.x * 256 + t;
    int v = (i < N) ? cnt_r_pad[i * PAD] : 0;
    sh[t] = v;
    __syncthreads();
    for (int off = 1; off < 256; off <<= 1) {
        int u = (t >= off) ? sh[t - off] : 0;
        __syncthreads();
        sh[t] += u;
        __syncthreads();
    }
    if (i < N) {
        int excl = sh[t] - v + boff[blockIdx.x];
        row_start[i] = excl;
        if (i == N - 1) row_start[N] = excl + v;
        float od = (float)(v + 1);
        float onorm = rsqrtf(od);
        sscale[i] = onorm;
        int ds = cnt_s_pad[i * PAD];
        fin2[i] = make_float2(onorm, rsqrtf((float)(ds + 1)) / od);
    }
}

// ---------------------------------------------------------------------------
// Atomic-free fill: pos = row_start[receiver] + rank (rank from prep).
// ---------------------------------------------------------------------------
__global__ void fill_kernel(const int* __restrict__ senders,
                            const int* __restrict__ receivers,
                            const int* __restrict__ row_start,
                            const int* __restrict__ rank,
                            int* __restrict__ edge_src,
                            int E) {
    int e = blockIdx.x * blockDim.x + threadIdx.x;
    if (e < E) {
        int r = receivers[e];
        edge_src[row_start[r] + rank[e]] = senders[e];
    }
}

// ---------------------------------------------------------------------------
// Pull-gather + finalize in bf16: one wave per node, lane owns 2 dims (uint).
// Unroll x8 with independent loads for memory-level parallelism.
// ---------------------------------------------------------------------------
__global__ __launch_bounds__(256) void gather_kernel(
        const unsigned int* __restrict__ xb,     // [NP][64] uints (2 bf16 each)
        const int* __restrict__ edge_src,
        const int* __restrict__ row_start,       // [N+1]
        const float* __restrict__ sscale,        // [N]
        const float2* __restrict__ fin2,         // [N]
        unsigned int* __restrict__ aggb,         // [NP][64] uints
        int N) {
    int lane = threadIdx.x & 63;
    int n = (blockIdx.x * blockDim.x + threadIdx.x) >> 6;
    if (n >= N) return;

    int start = row_start[n];
    int deg   = row_start[n + 1] - start;
    float ax = 0.f, ay = 0.f;

    for (int base = 0; base < deg; base += 64) {
        int cnt = deg - base; if (cnt > 64) cnt = 64;
        int   src = 0;
        float sc  = 0.f;
        if (lane < cnt) {
            src = edge_src[start + base + lane];
            sc  = sscale[src];
        }
        int j = 0;
        for (; j + 8 <= cnt; j += 8) {
            int ss[8]; float cc[8]; unsigned int uu[8];
#pragma unroll
            for (int q = 0; q < 8; q++) {
                ss[q] = __shfl(src, j + q);
                cc[q] = __shfl(sc,  j + q);
            }
#pragma unroll
            for (int q = 0; q < 8; q++)
                uu[q] = xb[(size_t)ss[q] * 64 + lane];
#pragma unroll
            for (int q = 0; q < 8; q++) {
                ax += bf_lo(uu[q]) * cc[q];
                ay += bf_hi(uu[q]) * cc[q];
            }
        }
        for (; j < cnt; j++) {
            int   s = __shfl(src, j);
            float c = __shfl(sc, j);
            unsigned int u = xb[(size_t)s * 64 + lane];
            ax += bf_lo(u) * c;
            ay += bf_hi(u) * c;
        }
    }

    float2 f = fin2[n];
    unsigned int u = xb[(size_t)n * 64 + lane];
    ax = (ax + bf_lo(u) * f.x) * f.y;
    ay = (ay + bf_hi(u) * f.x) * f.y;
    aggb[(size_t)n * 64 + lane] =
        (unsigned int)f2bf(ax) | ((unsigned int)f2bf(ay) << 16);
}

// ---------------------------------------------------------------------------
// MFMA bf16 GEMM: out = [x_bf | agg_bf] @ W_bf^T + b  (fp32 accum/output).
// Block 128x128, 4 waves in 2x2; each wave 4x4 tiles of 16x16x32 mfma.
// C/D layout: col = lane&15, row = (lane>>4)*4 + reg   [m89/m91-verified].
// ---------------------------------------------------------------------------
__global__ __launch_bounds__(256) void gemm_kernel(
        const unsigned short* __restrict__ x_bf,   // [NP][128]
        const unsigned short* __restrict__ agg_bf, // [NP][128]
        const unsigned short* __restrict__ W_bf,   // [128][256]
        const float* __restrict__ bias,
        float* __restrict__ out, int N) {
    __shared__ unsigned short As[BM * BK];    // 8 KB
    __shared__ unsigned short Bs[DIM * BK];   // 8 KB

    int t    = threadIdx.x;
    int lane = t & 63;
    int w    = t >> 6;
    int wr   = w >> 1, wc = w & 1;
    int row0 = blockIdx.x * BM;

    f32x4 acc[4][4];
#pragma unroll
    for (int i = 0; i < 4; i++)
#pragma unroll
        for (int j = 0; j < 4; j++) acc[i][j] = (f32x4){0.f, 0.f, 0.f, 0.f};

    for (int kt = 0; kt < 8; kt++) {
        const unsigned short* src = (kt < 4) ? x_bf : agg_bf;
        int k0 = (kt & 3) * BK;
#pragma unroll
        for (int p = 0; p < 2; p++) {
            int idx = p * 256 + t;
            int row = idx >> 2;
            int ch  = idx & 3;
            uint4 v = *(const uint4*)&src[(size_t)(row0 + row) * 128 + k0 + ch * 8];
            *(uint4*)&As[row * BK + ch * 8] = v;
        }
#pragma unroll
        for (int p = 0; p < 2; p++) {
            int idx = p * 256 + t;
            int n   = idx >> 2;
            int ch  = idx & 3;
            uint4 v = *(const uint4*)&W_bf[(size_t)n * 256 + kt * BK + ch * 8];
            *(uint4*)&Bs[n * BK + ch * 8] = v;
        }
        __syncthreads();

        short8 a[4], b[4];
#pragma unroll
        for (int i = 0; i < 4; i++)
            a[i] = *(const short8*)&As[(wr * 64 + i * 16 + (lane & 15)) * BK + (lane >> 4) * 8];
#pragma unroll
        for (int j = 0; j < 4; j++)
            b[j] = *(const short8*)&Bs[(wc * 64 + j * 16 + (lane & 15)) * BK + (lane >> 4) * 8];
#pragma unroll
        for (int i = 0; i < 4; i++)
#pragma unroll
            for (int j = 0; j < 4; j++)
                acc[i][j] = __builtin_amdgcn_mfma_f32_16x16x32_bf16(a[i], b[j], acc[i][j], 0, 0, 0);
        __syncthreads();
    }

    int cq = lane >> 4;
    int cl = lane & 15;
#pragma unroll
    for (int j = 0; j < 4; j++) {
        int col = wc * 64 + j * 16 + cl;
        float bb = bias[col];
#pragma unroll
        for (int i = 0; i < 4; i++) {
            int rbase = row0 + wr * 64 + i * 16 + cq * 4;
#pragma unroll
            for (int r = 0; r < 4; r++) {
                int row = rbase + r;
                if (row < N) out[(size_t)row * DIM + col] = acc[i][j][r] + bb;
            }
        }
    }
}

// ---------------------------------------------------------------------------
// Launch
// ---------------------------------------------------------------------------
extern "C" void kernel_launch(void* const* d_in, const int* in_sizes, int n_in,
                              void* d_out, int out_size, void* d_ws, size_t ws_size,
                              hipStream_t stream) {
    const float* x         = (const float*)d_in[0];
    const int*   senders   = (const int*)d_in[1];
    const int*   receivers = (const int*)d_in[2];
    const float* W         = (const float*)d_in[4];
    const float* bias      = (const float*)d_in[5];
    float*       out       = (float*)d_out;

    int N  = in_sizes[0] / DIM;            // 50000
    int E  = in_sizes[1];                  // 625000
    int NB = (N + 255) / 256;              // 196 (must be <= 256)
    int NP = ((N + BM - 1) / BM) * BM;     // 50048 padded rows

    // Workspace layout, 256B-aligned chunks.
    char* ws = (char*)d_ws;
    size_t off = 0;
    #define WS_ALLOC(ptrtype, name, bytes) \
        ptrtype name = (ptrtype)(ws + off); off += (((size_t)(bytes)) + 255) & ~(size_t)255;
    WS_ALLOC(int*,            cnt_r_pad, (size_t)N * PAD * 4)   // zeroed
    WS_ALLOC(int*,            cnt_s_pad, (size_t)N * PAD * 4)   // zeroed
    WS_ALLOC(int*,            row_start, (size_t)(N + 1) * 4)
    WS_ALLOC(int*,            rank,      (size_t)E * 4)
    WS_ALLOC(int*,            bsum,      4096)
    WS_ALLOC(int*,            boff,      4096)
    WS_ALLOC(int*,            edge_src,  (size_t)E * 4)
    WS_ALLOC(float*,          sscale,    (size_t)N * 4)
    WS_ALLOC(float2*,         fin2,      (size_t)N * 8)
    WS_ALLOC(unsigned short*, x_bf,      (size_t)NP * DIM * 2)
    WS_ALLOC(unsigned short*, agg_bf,    (size_t)NP * DIM * 2)
    WS_ALLOC(unsigned short*, W_bf,      (size_t)DIM * 256 * 2)
    #undef WS_ALLOC

    // Zero the two padded counter arrays (contiguous at ws start).
    hipMemsetAsync(ws, 0, (size_t)N * PAD * 8, stream);

    int nx4 = N * 32;          // float4 count of x
    int nw4 = DIM * 256 / 4;   // float4 count of W = 8192
    int prep_threads = (nx4 > E) ? nx4 : E;
    prep_kernel<<<(prep_threads + 255) / 256, 256, 0, stream>>>(
        (const float4*)x, (const float4*)W, senders, receivers,
        (uint2*)x_bf, (uint2*)W_bf, cnt_r_pad, cnt_s_pad, rank, nx4, nw4, E);
    scan_phase_a<<<NB, 256, 0, stream>>>(cnt_r_pad, bsum, N);
    scan_phase_b<<<1, 256, 0, stream>>>(bsum, boff, NB);
    scan_phase_c<<<NB, 256, 0, stream>>>(cnt_r_pad, cnt_s_pad, boff,
                                         row_start, sscale, fin2, N);
    fill_kernel<<<(E + 255) / 256, 256, 0, stream>>>(senders, receivers,
                                                     row_start, rank, edge_src, E);
    gather_kernel<<<(N * 64 + 255) / 256, 256, 0, stream>>>(
        (const unsigned int*)x_bf, edge_src, row_start, sscale, fin2,
        (unsigned int*)agg_bf, N);
    gemm_kernel<<<(N + BM - 1) / BM, 256, 0, stream>>>(
        x_bf, agg_bf, W_bf, bias, out, N);
}

// Round 8
// 181.707 us; speedup vs baseline: 4.0339x; 1.0981x over previous
//
#include <hip/hip_runtime.h>

#define DIM 128
#define BM 128
#define BK 32
#define BINSZ 128      // nodes per coarse bin
#define EPB 2048       // edges per histogram/scatter block

typedef __attribute__((ext_vector_type(8))) short short8;
typedef __attribute__((ext_vector_type(4))) float f32x4;

// bf16 helpers (RNE), values are finite.
__device__ __forceinline__ unsigned short f2bf(float f) {
    unsigned int b = __float_as_uint(f);
    return (unsigned short)((b + 0x7fffu + ((b >> 16) & 1u)) >> 16);
}
__device__ __forceinline__ float bf_lo(unsigned int u) { return __uint_as_float(u << 16); }
__device__ __forceinline__ float bf_hi(unsigned int u) { return __uint_as_float(u & 0xffff0000u); }
__device__ __forceinline__ unsigned int pack2(float a, float b) {
    return (unsigned int)f2bf(a) | ((unsigned int)f2bf(b) << 16);
}
__device__ __forceinline__ uint2 pack4(float4 v) {
    uint2 r; r.x = pack2(v.x, v.y); r.y = pack2(v.z, v.w); return r;
}

// ---------------------------------------------------------------------------
// Convert x -> x_bf, W -> W_bf. Pure streaming, no atomics.
// ---------------------------------------------------------------------------
__global__ void convert_kernel(const float4* __restrict__ x4,
                               const float4* __restrict__ W4,
                               uint2* __restrict__ xb4,
                               uint2* __restrict__ Wb4,
                               int nx4, int nw4) {
    int i = blockIdx.x * blockDim.x + threadIdx.x;
    if (i < nx4) xb4[i] = pack4(x4[i]);
    if (i < nw4) Wb4[i] = pack4(W4[i]);
}

// ---------------------------------------------------------------------------
// A1: coarse dual histogram (receiver>>7, sender>>7) via LDS, flushed with
// ~2*nbin global atomics per block (~240K total vs 2.5M before).
// ---------------------------------------------------------------------------
__global__ __launch_bounds__(256) void coarse_hist_kernel(
        const int* __restrict__ senders, const int* __restrict__ receivers,
        int* __restrict__ ccr, int* __restrict__ ccs, int E, int nbin) {
    __shared__ int hr[512], hs[512];
    int t = threadIdx.x;
    for (int b = t; b < nbin; b += 256) { hr[b] = 0; hs[b] = 0; }
    __syncthreads();
    int base = blockIdx.x * EPB;
    for (int k = 0; k < EPB; k += 256) {
        int e = base + k + t;
        if (e < E) {
            atomicAdd(&hr[receivers[e] >> 7], 1);
            atomicAdd(&hs[senders[e] >> 7], 1);
        }
    }
    __syncthreads();
    for (int b = t; b < nbin; b += 256) {
        if (hr[b]) atomicAdd(&ccr[b], hr[b]);
        if (hs[b]) atomicAdd(&ccs[b], hs[b]);
    }
}

// ---------------------------------------------------------------------------
// S: scan both coarse histograms -> startR/startS (+cursors); row_start[N]=E.
// ---------------------------------------------------------------------------
__global__ __launch_bounds__(512) void coarse_scan_kernel(
        const int* __restrict__ ccr, const int* __restrict__ ccs,
        int* __restrict__ startR, int* __restrict__ startS,
        int* __restrict__ curR, int* __restrict__ curS,
        int* __restrict__ row_start, int nbin, int N, int E) {
    __shared__ int sh[1024];
    int t = threadIdx.x;
    int vr = (t < nbin) ? ccr[t] : 0;
    int vs = (t < nbin) ? ccs[t] : 0;
    sh[t] = vr; sh[512 + t] = vs;
    __syncthreads();
    for (int off = 1; off < 512; off <<= 1) {
        int ur = (t >= off) ? sh[t - off] : 0;
        int us = (t >= off) ? sh[512 + t - off] : 0;
        __syncthreads();
        sh[t] += ur; sh[512 + t] += us;
        __syncthreads();
    }
    if (t < nbin) {
        int er = sh[t] - vr, es = sh[512 + t] - vs;
        startR[t] = er; curR[t] = er;
        startS[t] = es; curS[t] = es;
    }
    if (t == 0) { startR[nbin] = E; startS[nbin] = E; row_start[N] = E; }
}

// ---------------------------------------------------------------------------
// A2: dual scatter into coarse buckets. Per-block LDS hist -> one global
// atomic per (block,bin) for the base -> LDS cursors -> plain stores.
// Receiver bucket entry packs ((r&127)<<16)|s (both fit 16 bits).
// ---------------------------------------------------------------------------
__global__ __launch_bounds__(256) void coarse_scatter_kernel(
        const int* __restrict__ senders, const int* __restrict__ receivers,
        int* __restrict__ curR, int* __restrict__ curS,
        unsigned int* __restrict__ bucket_r,   // [E] packed (rl<<16)|s
        int* __restrict__ bucket_s,            // [E] sender values
        int E, int nbin) {
    __shared__ int hr[512], hs[512];
    __shared__ int br_[512], bs_[512];
    int t = threadIdx.x;
    for (int b = t; b < nbin; b += 256) { hr[b] = 0; hs[b] = 0; }
    __syncthreads();
    int base = blockIdx.x * EPB;
    for (int k = 0; k < EPB; k += 256) {
        int e = base + k + t;
        if (e < E) {
            atomicAdd(&hr[receivers[e] >> 7], 1);
            atomicAdd(&hs[senders[e] >> 7], 1);
        }
    }
    __syncthreads();
    for (int b = t; b < nbin; b += 256) {
        br_[b] = hr[b] ? atomicAdd(&curR[b], hr[b]) : 0;
        bs_[b] = hs[b] ? atomicAdd(&curS[b], hs[b]) : 0;
    }
    __syncthreads();
    for (int k = 0; k < EPB; k += 256) {
        int e = base + k + t;
        if (e < E) {
            int s = senders[e], r = receivers[e];
            int pr = atomicAdd(&br_[r >> 7], 1);
            bucket_r[pr] = ((unsigned int)(r & 127) << 16) | (unsigned int)s;
            int ps = atomicAdd(&bs_[s >> 7], 1);
            bucket_s[ps] = s;
        }
    }
}

// ---------------------------------------------------------------------------
// BR: per coarse bin, fine count + LDS scan -> row_start; rank via LDS
// cursor -> edge_src (final CSR). All-LDS atomics.
// ---------------------------------------------------------------------------
__global__ __launch_bounds__(256) void fine_r_kernel(
        const unsigned int* __restrict__ bucket_r,
        const int* __restrict__ startR,
        int* __restrict__ edge_src,
        int* __restrict__ row_start, int N) {
    __shared__ int fine[BINSZ];
    __shared__ int fstart[BINSZ];
    int b = blockIdx.x, t = threadIdx.x;
    if (t < BINSZ) fine[t] = 0;
    __syncthreads();
    int lo = startR[b], hi = startR[b + 1];
    for (int i = lo + t; i < hi; i += 256)
        atomicAdd(&fine[bucket_r[i] >> 16], 1);
    __syncthreads();
    if (t < BINSZ) fstart[t] = fine[t];
    __syncthreads();
    for (int off = 1; off < BINSZ; off <<= 1) {
        int u = (t < BINSZ && t >= off) ? fstart[t - off] : 0;
        __syncthreads();
        if (t < BINSZ) fstart[t] += u;
        __syncthreads();
    }
    if (t < BINSZ) {
        int excl = fstart[t] - fine[t];
        int node = b * BINSZ + t;
        if (node < N) row_start[node] = lo + excl;
        fstart[t] = excl;   // becomes the scatter cursor
    }
    __syncthreads();
    for (int i = lo + t; i < hi; i += 256) {
        unsigned int u = bucket_r[i];
        int pos = atomicAdd(&fstart[u >> 16], 1);
        edge_src[lo + pos] = (int)(u & 0xFFFFu);
    }
}

// ---------------------------------------------------------------------------
// BS: per coarse bin, fine sender count -> cnt_s. All-LDS atomics.
// ---------------------------------------------------------------------------
__global__ __launch_bounds__(256) void fine_s_kernel(
        const int* __restrict__ bucket_s,
        const int* __restrict__ startS,
        int* __restrict__ cnt_s, int N) {
    __shared__ int fine[BINSZ];
    int b = blockIdx.x, t = threadIdx.x;
    if (t < BINSZ) fine[t] = 0;
    __syncthreads();
    int lo = startS[b], hi = startS[b + 1];
    for (int i = lo + t; i < hi; i += 256)
        atomicAdd(&fine[bucket_s[i] & 127], 1);
    __syncthreads();
    if (t < BINSZ) {
        int node = b * BINSZ + t;
        if (node < N) cnt_s[node] = fine[t];
    }
}

// ---------------------------------------------------------------------------
// Prescale: xs[n] = bf16(x_bf[n] * rsqrt(deg_r+1)); fs[n] = rsqrt(cnt_s+1)/od.
// ---------------------------------------------------------------------------
__global__ __launch_bounds__(256) void prescale_kernel(
        const uint2* __restrict__ xb2,     // [N][32]
        const int* __restrict__ row_start,
        const int* __restrict__ cnt_s,
        uint2* __restrict__ xs2,           // [N][32]
        float* __restrict__ fs, int N) {
    int i = blockIdx.x * blockDim.x + threadIdx.x;
    int n = i >> 5, c = i & 31;
    if (n >= N) return;
    float od = (float)(row_start[n + 1] - row_start[n] + 1);
    float sc = rsqrtf(od);
    uint2 u = xb2[(size_t)n * 32 + c];
    uint2 o;
    o.x = pack2(bf_lo(u.x) * sc, bf_hi(u.x) * sc);
    o.y = pack2(bf_lo(u.y) * sc, bf_hi(u.y) * sc);
    xs2[(size_t)n * 32 + c] = o;
    if (c == 0) fs[n] = rsqrtf((float)(cnt_s[n] + 1)) / od;
}

// ---------------------------------------------------------------------------
// Gather: agg[n] = (sum_{src in CSR[n]} xs[src] + xs[n]) * fs[n].
// One wave per node; lane owns 2 dims; pure row-sum (no per-edge scales).
// ---------------------------------------------------------------------------
__global__ __launch_bounds__(256) void gather_kernel(
        const unsigned int* __restrict__ xs,     // [NP][64]
        const int* __restrict__ edge_src,
        const int* __restrict__ row_start,       // [N+1]
        const float* __restrict__ fs,            // [N]
        unsigned int* __restrict__ aggb,         // [NP][64]
        int N) {
    int lane = threadIdx.x & 63;
    int n = (blockIdx.x * blockDim.x + threadIdx.x) >> 6;
    if (n >= N) return;

    int start = row_start[n];
    int deg   = row_start[n + 1] - start;
    float ax = 0.f, ay = 0.f;

    for (int base = 0; base < deg; base += 64) {
        int cnt = deg - base; if (cnt > 64) cnt = 64;
        int src = 0;
        if (lane < cnt) src = edge_src[start + base + lane];
        int j = 0;
        for (; j + 8 <= cnt; j += 8) {
            int ss[8]; unsigned int uu[8];
#pragma unroll
            for (int q = 0; q < 8; q++) ss[q] = __shfl(src, j + q);
#pragma unroll
            for (int q = 0; q < 8; q++) uu[q] = xs[(size_t)ss[q] * 64 + lane];
#pragma unroll
            for (int q = 0; q < 8; q++) { ax += bf_lo(uu[q]); ay += bf_hi(uu[q]); }
        }
        for (; j < cnt; j++) {
            int s = __shfl(src, j);
            unsigned int u = xs[(size_t)s * 64 + lane];
            ax += bf_lo(u); ay += bf_hi(u);
        }
    }

    float f = fs[n];
    unsigned int u = xs[(size_t)n * 64 + lane];
    ax = (ax + bf_lo(u)) * f;
    ay = (ay + bf_hi(u)) * f;
    aggb[(size_t)n * 64 + lane] = pack2(ax, ay);
}

// ---------------------------------------------------------------------------
// MFMA bf16 GEMM: out = [x_bf | agg_bf] @ W_bf^T + b  (fp32 accum/output).
// ---------------------------------------------------------------------------
__global__ __launch_bounds__(256) void gemm_kernel(
        const unsigned short* __restrict__ x_bf,   // [NP][128]
        const unsigned short* __restrict__ agg_bf, // [NP][128]
        const unsigned short* __restrict__ W_bf,   // [128][256]
        const float* __restrict__ bias,
        float* __restrict__ out, int N) {
    __shared__ unsigned short As[BM * BK];
    __shared__ unsigned short Bs[DIM * BK];

    int t    = threadIdx.x;
    int lane = t & 63;
    int w    = t >> 6;
    int wr   = w >> 1, wc = w & 1;
    int row0 = blockIdx.x * BM;

    f32x4 acc[4][4];
#pragma unroll
    for (int i = 0; i < 4; i++)
#pragma unroll
        for (int j = 0; j < 4; j++) acc[i][j] = (f32x4){0.f, 0.f, 0.f, 0.f};

    for (int kt = 0; kt < 8; kt++) {
        const unsigned short* src = (kt < 4) ? x_bf : agg_bf;
        int k0 = (kt & 3) * BK;
#pragma unroll
        for (int p = 0; p < 2; p++) {
            int idx = p * 256 + t;
            int row = idx >> 2;
            int ch  = idx & 3;
            uint4 v = *(const uint4*)&src[(size_t)(row0 + row) * 128 + k0 + ch * 8];
            *(uint4*)&As[row * BK + ch * 8] = v;
        }
#pragma unroll
        for (int p = 0; p < 2; p++) {
            int idx = p * 256 + t;
            int n   = idx >> 2;
            int ch  = idx & 3;
            uint4 v = *(const uint4*)&W_bf[(size_t)n * 256 + kt * BK + ch * 8];
            *(uint4*)&Bs[n * BK + ch * 8] = v;
        }
        __syncthreads();

        short8 a[4], b[4];
#pragma unroll
        for (int i = 0; i < 4; i++)
            a[i] = *(const short8*)&As[(wr * 64 + i * 16 + (lane & 15)) * BK + (lane >> 4) * 8];
#pragma unroll
        for (int j = 0; j < 4; j++)
            b[j] = *(const short8*)&Bs[(wc * 64 + j * 16 + (lane & 15)) * BK + (lane >> 4) * 8];
#pragma unroll
        for (int i = 0; i < 4; i++)
#pragma unroll
            for (int j = 0; j < 4; j++)
                acc[i][j] = __builtin_amdgcn_mfma_f32_16x16x32_bf16(a[i], b[j], acc[i][j], 0, 0, 0);
        __syncthreads();
    }

    int cq = lane >> 4;
    int cl = lane & 15;
#pragma unroll
    for (int j = 0; j < 4; j++) {
        int col = wc * 64 + j * 16 + cl;
        float bb = bias[col];
#pragma unroll
        for (int i = 0; i < 4; i++) {
            int rbase = row0 + wr * 64 + i * 16 + cq * 4;
#pragma unroll
            for (int r = 0; r < 4; r++) {
                int row = rbase + r;
                if (row < N) out[(size_t)row * DIM + col] = acc[i][j][r] + bb;
            }
        }
    }
}

// ---------------------------------------------------------------------------
// Launch
// ---------------------------------------------------------------------------
extern "C" void kernel_launch(void* const* d_in, const int* in_sizes, int n_in,
                              void* d_out, int out_size, void* d_ws, size_t ws_size,
                              hipStream_t stream) {
    const float* x         = (const float*)d_in[0];
    const int*   senders   = (const int*)d_in[1];
    const int*   receivers = (const int*)d_in[2];
    const float* W         = (const float*)d_in[4];
    const float* bias      = (const float*)d_in[5];
    float*       out       = (float*)d_out;

    int N    = in_sizes[0] / DIM;              // 50000
    int E    = in_sizes[1];                    // 625000
    int nbin = (N + BINSZ - 1) / BINSZ;        // 391  (<= 512)
    int NAB  = (E + EPB - 1) / EPB;            // 306
    int NP   = ((N + BM - 1) / BM) * BM;       // 50048

    // Workspace layout, 256B-aligned chunks. Buckets alias agg_bf (dead
    // before gather writes agg).
    char* ws = (char*)d_ws;
    size_t off = 0;
    #define WS_ALLOC(ptrtype, name, bytes) \
        ptrtype name = (ptrtype)(ws + off); off += (((size_t)(bytes)) + 255) & ~(size_t)255;
    WS_ALLOC(int*,            ccr,       (size_t)nbin * 4)          // zeroed
    WS_ALLOC(int*,            ccs,       (size_t)nbin * 4)          // zeroed
    size_t zero_end = off;   // R7 BUG FIX: zero through the PADDED end of ccs
    WS_ALLOC(int*,            startR,    (size_t)(nbin + 1) * 4)
    WS_ALLOC(int*,            startS,    (size_t)(nbin + 1) * 4)
    WS_ALLOC(int*,            curR,      (size_t)nbin * 4)
    WS_ALLOC(int*,            curS,      (size_t)nbin * 4)
    WS_ALLOC(int*,            row_start, (size_t)(N + 1) * 4)
    WS_ALLOC(int*,            cnt_s,     (size_t)N * 4)
    WS_ALLOC(float*,          fs,        (size_t)N * 4)
    WS_ALLOC(int*,            edge_src,  (size_t)E * 4)
    WS_ALLOC(unsigned short*, x_bf,      (size_t)NP * DIM * 2)
    WS_ALLOC(unsigned short*, xs_bf,     (size_t)NP * DIM * 2)
    WS_ALLOC(unsigned short*, agg_bf,    (size_t)NP * DIM * 2)
    WS_ALLOC(unsigned short*, W_bf,      (size_t)DIM * 256 * 2)
    #undef WS_ALLOC

    unsigned int* bucket_r = (unsigned int*)agg_bf;                       // 4E bytes
    int*          bucket_s = (int*)((char*)agg_bf + (((size_t)E * 4 + 255) & ~(size_t)255));

    // Zero both coarse histograms INCLUDING alignment padding.
    hipMemsetAsync(ws, 0, zero_end, stream);

    int nx4 = N * 32;          // float4 count of x
    int nw4 = DIM * 256 / 4;   // 8192
    convert_kernel<<<(nx4 + 255) / 256, 256, 0, stream>>>(
        (const float4*)x, (const float4*)W, (uint2*)x_bf, (uint2*)W_bf, nx4, nw4);
    coarse_hist_kernel<<<NAB, 256, 0, stream>>>(senders, receivers, ccr, ccs, E, nbin);
    coarse_scan_kernel<<<1, 512, 0, stream>>>(ccr, ccs, startR, startS,
                                              curR, curS, row_start, nbin, N, E);
    coarse_scatter_kernel<<<NAB, 256, 0, stream>>>(senders, receivers, curR, curS,
                                                   bucket_r, bucket_s, E, nbin);
    fine_r_kernel<<<nbin, 256, 0, stream>>>(bucket_r, startR, edge_src, row_start, N);
    fine_s_kernel<<<nbin, 256, 0, stream>>>(bucket_s, startS, cnt_s, N);
    prescale_kernel<<<(N * 32 + 255) / 256, 256, 0, stream>>>(
        (const uint2*)x_bf, row_start, cnt_s, (uint2*)xs_bf, fs, N);
    gather_kernel<<<(N * 64 + 255) / 256, 256, 0, stream>>>(
        (const unsigned int*)xs_bf, edge_src, row_start, fs,
        (unsigned int*)agg_bf, N);
    gemm_kernel<<<(N + BM - 1) / BM, 256, 0, stream>>>(
        x_bf, agg_bf, W_bf, bias, out, N);
}

// Round 10
// 177.716 us; speedup vs baseline: 4.1245x; 1.0225x over previous
//
#include <hip/hip_runtime.h>

#define DIM 128
#define BM 128
#define BK 32
#define BINSZ 128      // nodes per coarse bin
#define EPB 2048       // edges per histogram/scatter block

typedef __attribute__((ext_vector_type(8))) short short8;
typedef __attribute__((ext_vector_type(4))) float f32x4;

// bf16 helpers (RNE), values are finite.
__device__ __forceinline__ unsigned short f2bf(float f) {
    unsigned int b = __float_as_uint(f);
    return (unsigned short)((b + 0x7fffu + ((b >> 16) & 1u)) >> 16);
}
__device__ __forceinline__ float bf_lo(unsigned int u) { return __uint_as_float(u << 16); }
__device__ __forceinline__ float bf_hi(unsigned int u) { return __uint_as_float(u & 0xffff0000u); }
__device__ __forceinline__ unsigned int pack2(float a, float b) {
    return (unsigned int)f2bf(a) | ((unsigned int)f2bf(b) << 16);
}
__device__ __forceinline__ uint2 pack4(float4 v) {
    uint2 r; r.x = pack2(v.x, v.y); r.y = pack2(v.z, v.w); return r;
}

// ---------------------------------------------------------------------------
// Convert x -> x_bf, W -> W_bf. Pure streaming.
// ---------------------------------------------------------------------------
__global__ void convert_kernel(const float4* __restrict__ x4,
                               const float4* __restrict__ W4,
                               uint2* __restrict__ xb4,
                               uint2* __restrict__ Wb4,
                               int nx4, int nw4) {
    int i = blockIdx.x * blockDim.x + threadIdx.x;
    if (i < nx4) xb4[i] = pack4(x4[i]);
    if (i < nw4) Wb4[i] = pack4(W4[i]);
}

// ---------------------------------------------------------------------------
// Per-block dual histogram -> H[blk][bin] (no global atomics).
// ---------------------------------------------------------------------------
__global__ __launch_bounds__(256) void hist_kernel(
        const int* __restrict__ senders, const int* __restrict__ receivers,
        int* __restrict__ Hr, int* __restrict__ Hs, int E, int nbin) {
    __shared__ int hr[512], hs[512];
    int t = threadIdx.x;
    for (int b = t; b < nbin; b += 256) { hr[b] = 0; hs[b] = 0; }
    __syncthreads();
    int base = blockIdx.x * EPB;
    for (int k = 0; k < EPB; k += 256) {
        int e = base + k + t;
        if (e < E) {
            atomicAdd(&hr[receivers[e] >> 7], 1);
            atomicAdd(&hs[senders[e] >> 7], 1);
        }
    }
    __syncthreads();
    size_t ho = (size_t)blockIdx.x * nbin;
    for (int b = t; b < nbin; b += 256) {
        Hr[ho + b] = hr[b];
        Hs[ho + b] = hs[b];
    }
}

// ---------------------------------------------------------------------------
// Per-bin scan over blocks: H[blk][bin] -> exclusive prefix (in place) and
// per-bin totals. One block per bin, handles R and S sides.
// ---------------------------------------------------------------------------
__global__ __launch_bounds__(512) void scan_bins_kernel(
        int* __restrict__ Hr, int* __restrict__ Hs,
        int* __restrict__ tot_r, int* __restrict__ tot_s,
        int NAB, int nbin) {
    __shared__ int sr[512], ss[512];
    int b = blockIdx.x, t = threadIdx.x;
    int vr = (t < NAB) ? Hr[(size_t)t * nbin + b] : 0;
    int vs = (t < NAB) ? Hs[(size_t)t * nbin + b] : 0;
    sr[t] = vr; ss[t] = vs;
    __syncthreads();
    for (int off = 1; off < 512; off <<= 1) {
        int ur = (t >= off) ? sr[t - off] : 0;
        int us = (t >= off) ? ss[t - off] : 0;
        __syncthreads();
        sr[t] += ur; ss[t] += us;
        __syncthreads();
    }
    if (t < NAB) {
        Hr[(size_t)t * nbin + b] = sr[t] - vr;   // exclusive prefix
        Hs[(size_t)t * nbin + b] = ss[t] - vs;
    }
    if (t == 511) { tot_r[b] = sr[511]; tot_s[b] = ss[511]; }
}

// ---------------------------------------------------------------------------
// Scan per-bin totals -> global bin bases; also row_start[N] = E.
// ---------------------------------------------------------------------------
__global__ __launch_bounds__(512) void scan_base_kernel(
        const int* __restrict__ tot_r, const int* __restrict__ tot_s,
        int* __restrict__ base_r, int* __restrict__ base_s,
        int* __restrict__ row_start, int nbin, int N, int E) {
    __shared__ int sr[512], ss[512];
    int t = threadIdx.x;
    int vr = (t < nbin) ? tot_r[t] : 0;
    int vs = (t < nbin) ? tot_s[t] : 0;
    sr[t] = vr; ss[t] = vs;
    __syncthreads();
    for (int off = 1; off < 512; off <<= 1) {
        int ur = (t >= off) ? sr[t - off] : 0;
        int us = (t >= off) ? ss[t - off] : 0;
        __syncthreads();
        sr[t] += ur; ss[t] += us;
        __syncthreads();
    }
    if (t < nbin) {
        base_r[t] = sr[t] - vr;
        base_s[t] = ss[t] - vs;
    }
    if (t == 0) { base_r[nbin] = E; base_s[nbin] = E; row_start[N] = E; }
}

// ---------------------------------------------------------------------------
// Scatter into coarse buckets. Cursors = base[b] + P[blk][b]; LDS atomics
// only, plain global stores. Receiver entry packs ((r&127)<<16)|s.
// ---------------------------------------------------------------------------
__global__ __launch_bounds__(256) void scatter_kernel(
        const int* __restrict__ senders, const int* __restrict__ receivers,
        const int* __restrict__ Hr, const int* __restrict__ Hs,
        const int* __restrict__ base_r, const int* __restrict__ base_s,
        unsigned int* __restrict__ bucket_r, int* __restrict__ bucket_s,
        int E, int nbin) {
    __shared__ int br_[512], bs_[512];
    int t = threadIdx.x;
    size_t ho = (size_t)blockIdx.x * nbin;
    for (int b = t; b < nbin; b += 256) {
        br_[b] = base_r[b] + Hr[ho + b];
        bs_[b] = base_s[b] + Hs[ho + b];
    }
    __syncthreads();
    int base = blockIdx.x * EPB;
    for (int k = 0; k < EPB; k += 256) {
        int e = base + k + t;
        if (e < E) {
            int s = senders[e], r = receivers[e];
            int pr = atomicAdd(&br_[r >> 7], 1);
            bucket_r[pr] = ((unsigned int)(r & 127) << 16) | (unsigned int)s;
            int ps = atomicAdd(&bs_[s >> 7], 1);
            bucket_s[ps] = s;
        }
    }
}

// ---------------------------------------------------------------------------
// Fused fine pass (one block per bin): receiver fine-sort -> row_start +
// edge_src; sender fine-count (LDS only) -> fs; prescale xs = x_bf * sc_r.
// ---------------------------------------------------------------------------
__global__ __launch_bounds__(256) void fine_kernel(
        const unsigned int* __restrict__ bucket_r,
        const int* __restrict__ bucket_s,
        const int* __restrict__ base_r,
        const int* __restrict__ base_s,
        const uint2* __restrict__ xb2,     // [N][32]
        int* __restrict__ edge_src,
        int* __restrict__ row_start,
        float* __restrict__ fs,
        uint2* __restrict__ xs2,           // [NP][32]
        int N) {
    __shared__ int fine[BINSZ], fstart[BINSZ], cs[BINSZ];
    __shared__ float scs[BINSZ];
    int b = blockIdx.x, t = threadIdx.x;
    if (t < BINSZ) { fine[t] = 0; cs[t] = 0; }
    __syncthreads();

    int loR = base_r[b], hiR = base_r[b + 1];
    int loS = base_s[b], hiS = base_s[b + 1];
    for (int i = loR + t; i < hiR; i += 256)
        atomicAdd(&fine[bucket_r[i] >> 16], 1);
    for (int i = loS + t; i < hiS; i += 256)
        atomicAdd(&cs[bucket_s[i] & 127], 1);
    __syncthreads();

    if (t < BINSZ) fstart[t] = fine[t];
    __syncthreads();
    for (int off = 1; off < BINSZ; off <<= 1) {
        int u = (t < BINSZ && t >= off) ? fstart[t - off] : 0;
        __syncthreads();
        if (t < BINSZ) fstart[t] += u;
        __syncthreads();
    }
    if (t < BINSZ) {
        int excl = fstart[t] - fine[t];
        int node = b * BINSZ + t;
        float od = (float)(fine[t] + 1);
        float sc = rsqrtf(od);
        scs[t] = sc;
        if (node < N) {
            row_start[node] = loR + excl;
            fs[node] = rsqrtf((float)(cs[t] + 1)) / od;
        }
        fstart[t] = excl;   // becomes the scatter cursor
    }
    __syncthreads();

    for (int i = loR + t; i < hiR; i += 256) {
        unsigned int u = bucket_r[i];
        int pos = atomicAdd(&fstart[u >> 16], 1);
        edge_src[loR + pos] = (int)(u & 0xFFFFu);
    }

    // Prescale this bin's 128 rows: 128 x 32 uint2.
    int nrow0 = b * BINSZ;
    for (int idx = t; idx < BINSZ * 32; idx += 256) {
        int row = idx >> 5, c = idx & 31;
        int node = nrow0 + row;
        if (node < N) {
            float sc = scs[row];
            uint2 u = xb2[(size_t)node * 32 + c];
            uint2 o;
            o.x = pack2(bf_lo(u.x) * sc, bf_hi(u.x) * sc);
            o.y = pack2(bf_lo(u.y) * sc, bf_hi(u.y) * sc);
            xs2[(size_t)node * 32 + c] = o;
        }
    }
}

// ---------------------------------------------------------------------------
// Gather: agg[n] = (sum_{src in CSR[n]} xs[src] + xs[n]) * fs[n].
// One wave per node; lane owns 2 dims; pure row-sum.
// ---------------------------------------------------------------------------
__global__ __launch_bounds__(256) void gather_kernel(
        const unsigned int* __restrict__ xs,     // [NP][64]
        const int* __restrict__ edge_src,
        const int* __restrict__ row_start,       // [N+1]
        const float* __restrict__ fs,            // [N]
        unsigned int* __restrict__ aggb,         // [NP][64]
        int N) {
    int lane = threadIdx.x & 63;
    int n = (blockIdx.x * blockDim.x + threadIdx.x) >> 6;
    if (n >= N) return;

    int start = row_start[n];
    int deg   = row_start[n + 1] - start;
    float ax = 0.f, ay = 0.f;

    for (int base = 0; base < deg; base += 64) {
        int cnt = deg - base; if (cnt > 64) cnt = 64;
        int src = 0;
        if (lane < cnt) src = edge_src[start + base + lane];
        int j = 0;
        for (; j + 8 <= cnt; j += 8) {
            int ss[8]; unsigned int uu[8];
#pragma unroll
            for (int q = 0; q < 8; q++) ss[q] = __shfl(src, j + q);
#pragma unroll
            for (int q = 0; q < 8; q++) uu[q] = xs[(size_t)ss[q] * 64 + lane];
#pragma unroll
            for (int q = 0; q < 8; q++) { ax += bf_lo(uu[q]); ay += bf_hi(uu[q]); }
        }
        for (; j < cnt; j++) {
            int s = __shfl(src, j);
            unsigned int u = xs[(size_t)s * 64 + lane];
            ax += bf_lo(u); ay += bf_hi(u);
        }
    }

    float f = fs[n];
    unsigned int u = xs[(size_t)n * 64 + lane];
    ax = (ax + bf_lo(u)) * f;
    ay = (ay + bf_hi(u)) * f;
    aggb[(size_t)n * 64 + lane] = pack2(ax, ay);
}

// ---------------------------------------------------------------------------
// MFMA bf16 GEMM, 512 threads: out = [x_bf | agg_bf] @ W_bf^T + b.
// Block 128x128, 8 waves in 2x4; each wave 4x2 tiles of 16x16x32 mfma.
// C/D layout: col = lane&15, row = (lane>>4)*4 + reg.
// ---------------------------------------------------------------------------
__global__ __launch_bounds__(512) void gemm_kernel(
        const unsigned short* __restrict__ x_bf,   // [NP][128]
        const unsigned short* __restrict__ agg_bf, // [NP][128]
        const unsigned short* __restrict__ W_bf,   // [128][256]
        const float* __restrict__ bias,
        float* __restrict__ out, int N) {
    __shared__ unsigned short As[BM * BK];
    __shared__ unsigned short Bs[DIM * BK];

    int t    = threadIdx.x;
    int lane = t & 63;
    int w    = t >> 6;           // 0..7
    int wr   = w >> 2, wc = w & 3;
    int row0 = blockIdx.x * BM;

    f32x4 acc[4][2];
#pragma unroll
    for (int i = 0; i < 4; i++)
#pragma unroll
        for (int j = 0; j < 2; j++) acc[i][j] = (f32x4){0.f, 0.f, 0.f, 0.f};

    for (int kt = 0; kt < 8; kt++) {
        const unsigned short* src = (kt < 4) ? x_bf : agg_bf;
        int k0 = (kt & 3) * BK;
        {   // stage A: 128 rows x 32 k in one 512-thread pass
            int row = t >> 2, ch = t & 3;
            uint4 v = *(const uint4*)&src[(size_t)(row0 + row) * 128 + k0 + ch * 8];
            *(uint4*)&As[row * BK + ch * 8] = v;
        }
        {   // stage B: 128 n x 32 k
            int n = t >> 2, ch = t & 3;
            uint4 v = *(const uint4*)&W_bf[(size_t)n * 256 + kt * BK + ch * 8];
            *(uint4*)&Bs[n * BK + ch * 8] = v;
        }
        __syncthreads();

        short8 a[4], b[2];
#pragma unroll
        for (int i = 0; i < 4; i++)
            a[i] = *(const short8*)&As[(wr * 64 + i * 16 + (lane & 15)) * BK + (lane >> 4) * 8];
#pragma unroll
        for (int j = 0; j < 2; j++)
            b[j] = *(const short8*)&Bs[(wc * 32 + j * 16 + (lane & 15)) * BK + (lane >> 4) * 8];
#pragma unroll
        for (int i = 0; i < 4; i++)
#pragma unroll
            for (int j = 0; j < 2; j++)
                acc[i][j] = __builtin_amdgcn_mfma_f32_16x16x32_bf16(a[i], b[j], acc[i][j], 0, 0, 0);
        __syncthreads();
    }

    int cq = lane >> 4;
    int cl = lane & 15;
#pragma unroll
    for (int j = 0; j < 2; j++) {
        int col = wc * 32 + j * 16 + cl;
        float bb = bias[col];
#pragma unroll
        for (int i = 0; i < 4; i++) {
            int rbase = row0 + wr * 64 + i * 16 + cq * 4;
#pragma unroll
            for (int r = 0; r < 4; r++) {
                int row = rbase + r;
                if (row < N) out[(size_t)row * DIM + col] = acc[i][j][r] + bb;
            }
        }
    }
}

// ---------------------------------------------------------------------------
// Launch
// ---------------------------------------------------------------------------
extern "C" void kernel_launch(void* const* d_in, const int* in_sizes, int n_in,
                              void* d_out, int out_size, void* d_ws, size_t ws_size,
                              hipStream_t stream) {
    const float* x         = (const float*)d_in[0];
    const int*   senders   = (const int*)d_in[1];
    const int*   receivers = (const int*)d_in[2];
    const float* W         = (const float*)d_in[4];
    const float* bias      = (const float*)d_in[5];
    float*       out       = (float*)d_out;

    int N    = in_sizes[0] / DIM;              // 50000
    int E    = in_sizes[1];                    // 625000
    int nbin = (N + BINSZ - 1) / BINSZ;        // 391  (<= 512)
    int NAB  = (E + EPB - 1) / EPB;            // 306  (<= 512)
    int NP   = ((N + BM - 1) / BM) * BM;       // 50048

    // Workspace layout, 256B-aligned chunks. Total ~41.41 MB (< R8's proven
    // 41.61 MB). Hr/Hs and both sort buckets ALIAS the agg_bf region: they
    // are dead before gather writes agg (hist/scan/scatter/fine all precede).
    char* ws = (char*)d_ws;
    size_t off = 0;
    #define WS_ALLOC(ptrtype, name, bytes) \
        ptrtype name = (ptrtype)(ws + off); off += (((size_t)(bytes)) + 255) & ~(size_t)255;
    WS_ALLOC(int*,            tot_r,     (size_t)nbin * 4)
    WS_ALLOC(int*,            tot_s,     (size_t)nbin * 4)
    WS_ALLOC(int*,            base_r,    (size_t)(nbin + 1) * 4)
    WS_ALLOC(int*,            base_s,    (size_t)(nbin + 1) * 4)
    WS_ALLOC(int*,            row_start, (size_t)(N + 1) * 4)
    WS_ALLOC(float*,          fs,        (size_t)N * 4)
    WS_ALLOC(int*,            edge_src,  (size_t)E * 4)
    WS_ALLOC(unsigned short*, x_bf,      (size_t)NP * DIM * 2)
    WS_ALLOC(unsigned short*, xs_bf,     (size_t)NP * DIM * 2)
    WS_ALLOC(unsigned short*, agg_bf,    (size_t)NP * DIM * 2)
    WS_ALLOC(unsigned short*, W_bf,      (size_t)DIM * 256 * 2)
    #undef WS_ALLOC

    // Aliases inside agg_bf (12.81 MB >= 2.5 + 2.5 + 0.48 + 0.48 MB):
    size_t eb = ((size_t)E * 4 + 255) & ~(size_t)255;
    size_t hb = ((size_t)NAB * nbin * 4 + 255) & ~(size_t)255;
    unsigned int* bucket_r = (unsigned int*)agg_bf;
    int*          bucket_s = (int*)((char*)agg_bf + eb);
    int*          Hr       = (int*)((char*)agg_bf + 2 * eb);
    int*          Hs       = (int*)((char*)agg_bf + 2 * eb + hb);

    int nx4 = N * 32;          // float4 count of x
    int nw4 = DIM * 256 / 4;   // 8192
    convert_kernel<<<(nx4 + 255) / 256, 256, 0, stream>>>(
        (const float4*)x, (const float4*)W, (uint2*)x_bf, (uint2*)W_bf, nx4, nw4);
    hist_kernel<<<NAB, 256, 0, stream>>>(senders, receivers, Hr, Hs, E, nbin);
    scan_bins_kernel<<<nbin, 512, 0, stream>>>(Hr, Hs, tot_r, tot_s, NAB, nbin);
    scan_base_kernel<<<1, 512, 0, stream>>>(tot_r, tot_s, base_r, base_s,
                                            row_start, nbin, N, E);
    scatter_kernel<<<NAB, 256, 0, stream>>>(senders, receivers, Hr, Hs,
                                            base_r, base_s, bucket_r, bucket_s, E, nbin);
    fine_kernel<<<nbin, 256, 0, stream>>>(bucket_r, bucket_s, base_r, base_s,
                                          (const uint2*)x_bf, edge_src, row_start,
                                          fs, (uint2*)xs_bf, N);
    gather_kernel<<<(N * 64 + 255) / 256, 256, 0, stream>>>(
        (const unsigned int*)xs_bf, edge_src, row_start, fs,
        (unsigned int*)agg_bf, N);
    gemm_kernel<<<(N + BM - 1) / BM, 512, 0, stream>>>(
        x_bf, agg_bf, W_bf, bias, out, N);
}